// Round 8
// baseline (302.772 us; speedup 1.0000x reference)
//
#include <hip/hip_runtime.h>
#include <cfloat>
#include <cmath>

#define NEG_SLOPE 0.01f

typedef __attribute__((ext_vector_type(8))) short short8;
typedef __attribute__((ext_vector_type(4))) float f32x4;

__device__ __forceinline__ float lrelu(float v) { return v >= 0.0f ? v : NEG_SLOPE * v; }

// f32 -> bf16 round-to-nearest-even (monotone; identity on exact bf16 values)
__device__ __forceinline__ ushort f2b(float f) {
    unsigned u = __float_as_uint(f);
    u += 0x7fffu + ((u >> 16) & 1u);
    return (ushort)(u >> 16);
}
__device__ __forceinline__ float b2f(ushort s) { return __uint_as_float(((unsigned)s) << 16); }

// split 8 consecutive f32 into hi/lo bf16 fragments (register-resident)
__device__ __forceinline__ void split8(const float* v, short8& hi, short8& lo) {
#pragma unroll
    for (int j = 0; j < 8; ++j) {
        ushort h = f2b(v[j]);
        hi[j] = (short)h;
        lo[j] = (short)f2b(v[j] - b2f(h));
    }
}

// ---- device-scope grid barrier (sense via generation counter) ---------------
// bar[0] = arrive count, bar[1] = generation. Must be zeroed before launch.
// All 256 blocks are co-resident (256 blocks <= 256 CUs, tiny LDS/VGPR).
__device__ __forceinline__ void gridbar(int* bar, int nblk, int& lgen) {
    __syncthreads();
    if (threadIdx.x == 0) {
        int prev = lgen;
        __threadfence();
        if (atomicAdd(&bar[0], 1) == nblk - 1) {
            atomicExch(&bar[0], 0);
            __threadfence();
            atomicAdd(&bar[1], 1);
        } else {
            while (atomicAdd(&bar[1], 0) <= prev) {}
        }
        lgen = prev + 1;
        __threadfence();
    }
    __syncthreads();
}

// ================= fused build: wprep + count + scan + partition + CSR =======
// grid MUST be 256 blocks x 256 threads.
// Buckets of 256 nodes by dst>>8; NBK = ceil(M/256) <= 256.
// G[bucket*256 + block] = per-block bucket counts -> exclusive scan in place.
__global__ __launch_bounds__(256, 1) void build_kernel(
    const int* __restrict__ ei,
    const float* __restrict__ Wh1, const float* __restrict__ Wf,
    const float* __restrict__ Wg1, const float* __restrict__ Wg2,
    ushort* __restrict__ WT, int* __restrict__ G, int* __restrict__ part,
    uint* __restrict__ bpairs, int* __restrict__ offs, int* __restrict__ srcs,
    int* __restrict__ bar, int E, int M, int NBK)
{
    __shared__ int sm[768];
    const int t = threadIdx.x;
    const int b = blockIdx.x;
    int lgen = 0;

    // ---- phase 0: weight prep (exactly 4*16384 = 65536 entries) ----
    {
        int tt = b * 256 + t;
        int mat = tt >> 14;
        int idx = tt & 16383;
        int n = idx >> 7, k = idx & 127;
        float v;
        if (mat == 0)      v = Wh1[k * 128 + n];
        else if (mat == 1) v = Wf[(k + 3) * 128 + n];
        else if (mat == 2) v = Wg1[k * 128 + n];
        else               v = Wg2[k * 128 + n];
        WT[(tt - idx) + n * 128 + k] = f2b(v);
    }

    // ---- phase 1: per-block bucket histogram ----
    sm[t] = 0;
    __syncthreads();
    for (int e = b * 256 + t; e < E; e += 65536)
        atomicAdd(&sm[ei[E + e] >> 8], 1);
    __syncthreads();
    if (t < NBK) G[t * 256 + b] = sm[t];
    gridbar(bar, 256, lgen);

    // ---- phase 2: bucket totals part[b] = sum of G row b ----
    if (b < NBK) {
        sm[t] = G[b * 256 + t];
        __syncthreads();
        for (int d = 128; d > 0; d >>= 1) {
            if (t < d) sm[t] += sm[t + d];
            __syncthreads();
        }
        if (t == 0) part[b] = sm[0];
    }
    gridbar(bar, 256, lgen);

    // ---- phase 3: every block computes exclusive bucket bases -> sm[512+*] ----
    {
        int v = (t < NBK) ? part[t] : 0;
        sm[256 + t] = v;
        __syncthreads();
        for (int d = 1; d < 256; d <<= 1) {
            int a = (t >= d) ? sm[256 + t - d] : 0;
            __syncthreads();
            sm[256 + t] += a;
            __syncthreads();
        }
        sm[512 + t] = sm[256 + t] - v;   // exclusive base of bucket t
        __syncthreads();
    }
    // ---- phase 3b: block b scans its own G row (exclusive, + base) ----
    if (b < NBK) {
        int v = G[b * 256 + t];
        sm[t] = v;
        __syncthreads();
        for (int d = 1; d < 256; d <<= 1) {
            int a = (t >= d) ? sm[t - d] : 0;
            __syncthreads();
            sm[t] += a;
            __syncthreads();
        }
        G[b * 256 + t] = sm[512 + b] + sm[t] - v;
    }
    gridbar(bar, 256, lgen);

    // ---- phase 4: partition edges into bucket regions ----
    if (t < NBK) sm[t] = G[t * 256 + b];   // this block's cursor per bucket
    __syncthreads();
    for (int e = b * 256 + t; e < E; e += 65536) {
        int src = ei[e];
        int dst = ei[E + e];
        int p = atomicAdd(&sm[dst >> 8], 1);
        bpairs[p] = (uint)src | ((uint)(dst & 255) << 24);
    }
    gridbar(bar, 256, lgen);

    // ---- phase 5: per-bucket local CSR (deg -> scan -> scatter) ----
    if (b < NBK) {
        int* deg = sm;
        int* scn = sm + 256;
        int* cur = sm + 512;
        const int base = G[b * 256];
        const int end  = (b + 1 < NBK) ? G[(b + 1) * 256] : E;
        deg[t] = 0;
        __syncthreads();
        for (int p = base + t; p < end; p += 256)
            atomicAdd(&deg[bpairs[p] >> 24], 1);
        __syncthreads();
        scn[t] = deg[t];
        __syncthreads();
        for (int d = 1; d < 256; d <<= 1) {
            int a = (t >= d) ? scn[t - d] : 0;
            __syncthreads();
            scn[t] += a;
            __syncthreads();
        }
        int excl = scn[t] - deg[t];
        cur[t] = excl;
        int node = b * 256 + t;
        if (node < M) offs[node] = base + excl;
        if (node == M - 1 || (b == NBK - 1 && t == 255)) offs[M] = E;
        __syncthreads();
        for (int p = base + t; p < end; p += 256) {
            uint pk = bpairs[p];
            int qpos = atomicAdd(&cur[pk >> 24], 1);
            srcs[base + qpos] = (int)(pk & 0xFFFFFFu);
        }
    }
}

// ---------------- MFMA GEMM skeleton ----------------
// block = 256 thr = 4 waves; tile 64 rows x 128 cols; K = 128 (4 steps of 32).
// wave w covers rows [w*16, w*16+16); lane: qd = L>>4, ln = L&15.
// A-operand in registers (hi/lo split, 2 MFMAs per fragment).
// b_frag: WT[n = nt*16+ln][k = ks*32+qd*8+j]  (LDS Bs, stride 136 bf16)
// D:      C[m = w*16+qd*4+r][n = nt*16+ln] = acc[nt][r]

#define GEMM_CORE_REG(ACC, AH, AL)                                              \
    {                                                                           \
        _Pragma("unroll")                                                       \
        for (int ks = 0; ks < 4; ++ks) {                                        \
            _Pragma("unroll")                                                   \
            for (int nt = 0; nt < 8; ++nt) {                                    \
                short8 bfr = *(const short8*)&Bs[(nt * 16 + ln) * 136 + ks * 32 + qd * 8]; \
                ACC[nt] = __builtin_amdgcn_mfma_f32_16x16x32_bf16(AL[ks], bfr, ACC[nt], 0, 0, 0); \
                ACC[nt] = __builtin_amdgcn_mfma_f32_16x16x32_bf16(AH[ks], bfr, ACC[nt], 0, 0, 0); \
            }                                                                   \
        }                                                                       \
    }

#define STAGE_B(WTP)                                                            \
    {                                                                           \
        _Pragma("unroll")                                                       \
        for (int i = 0; i < 8; ++i) {                                           \
            int c = tid + 256 * i;                                              \
            int r = c >> 4, col8 = (c & 15) * 8;                                \
            *(uint4*)&Bs[r * 136 + col8] = *(const uint4*)((WTP) + r * 128 + col8); \
        }                                                                       \
    }

// ---- fused: h1=lrelu(x@Wh1+bh1); q=tanh(h1@Wh2+bh2)-pos; y'=x@Wfx+pos.Wrel --
__global__ __launch_bounds__(256) void hy_kernel(
    const float* __restrict__ x, const ushort* __restrict__ Wh1T,
    const float* __restrict__ bh1, const float* __restrict__ Wh2,
    const float* __restrict__ bh2, const ushort* __restrict__ WfxT,
    const float* __restrict__ Wf, const float* __restrict__ pos,
    float* __restrict__ q, ushort* __restrict__ yb, int M)
{
    __shared__ ushort Bs[128 * 136];   // 34816 B
    __shared__ ushort yS[64 * 128];    // 16384 B  (51200 total -> 3 blocks/CU)
    const int tid = threadIdx.x;
    const int w = tid >> 6, L = tid & 63, qd = L >> 4, ln = L & 15;
    const int row0 = blockIdx.x * 64;
    const int arow = row0 + w * 16 + ln;

    // A fragments straight from global x, hi/lo split in regs
    short8 ah[4], al[4];
    {
        const float* base = x + (size_t)((arow < M) ? arow : 0) * 128 + qd * 8;
        float vb[8];
#pragma unroll
        for (int ks = 0; ks < 4; ++ks) {
            float4 v0 = make_float4(0.f, 0.f, 0.f, 0.f), v1 = v0;
            if (arow < M) {
                v0 = *(const float4*)(base + ks * 32);
                v1 = *(const float4*)(base + ks * 32 + 4);
            }
            vb[0] = v0.x; vb[1] = v0.y; vb[2] = v0.z; vb[3] = v0.w;
            vb[4] = v1.x; vb[5] = v1.y; vb[6] = v1.z; vb[7] = v1.w;
            split8(vb, ah[ks], al[ks]);
        }
    }

    STAGE_B(Wh1T);
    __syncthreads();
    f32x4 acc1[8];
#pragma unroll
    for (int nt = 0; nt < 8; ++nt) acc1[nt] = (f32x4){0.f, 0.f, 0.f, 0.f};
    GEMM_CORE_REG(acc1, ah, al);
    __syncthreads();

    STAGE_B(WfxT);
    __syncthreads();
    f32x4 acc2[8];
#pragma unroll
    for (int nt = 0; nt < 8; ++nt) acc2[nt] = (f32x4){0.f, 0.f, 0.f, 0.f};
    GEMM_CORE_REG(acc2, ah, al);
    __syncthreads();

    // h1 (f32) into Bs region; y' (bf16) into yS
    float* h1s = (float*)Bs;   // 64 x 132 f32 = 33792 B
#pragma unroll
    for (int nt = 0; nt < 8; ++nt) {
        int n = nt * 16 + ln;
        float bias = bh1[n];
#pragma unroll
        for (int r = 0; r < 4; ++r)
            h1s[(w * 16 + qd * 4 + r) * 132 + n] = lrelu(acc1[nt][r] + bias);
    }
#pragma unroll
    for (int r = 0; r < 4; ++r) {
        int m = w * 16 + qd * 4 + r;
        int gm = row0 + m;
        float p0 = 0.f, p1 = 0.f, p2 = 0.f;
        if (gm < M) { p0 = pos[gm * 3]; p1 = pos[gm * 3 + 1]; p2 = pos[gm * 3 + 2]; }
#pragma unroll
        for (int nt = 0; nt < 8; ++nt) {
            int n = nt * 16 + ln;
            yS[m * 128 + n] = f2b(acc2[nt][r] + p0 * Wf[n] + p1 * Wf[128 + n] + p2 * Wf[256 + n]);
        }
    }
    __syncthreads();

    // q reduction (threads 0..191)
    int row = tid & 63, cc = tid >> 6;
    if (cc < 3 && row0 + row < M) {
        float s = 0.f;
#pragma unroll
        for (int k4 = 0; k4 < 32; ++k4) {
            float4 h = *(const float4*)&h1s[row * 132 + k4 * 4];
            s += h.x * Wh2[(k4 * 4 + 0) * 3 + cc] + h.y * Wh2[(k4 * 4 + 1) * 3 + cc]
               + h.z * Wh2[(k4 * 4 + 2) * 3 + cc] + h.w * Wh2[(k4 * 4 + 3) * 3 + cc];
        }
        q[(row0 + row) * 3 + cc] = tanhf(s + bh2[cc]) - pos[(row0 + row) * 3 + cc];
    }
    // y' copy-out: 1024 x 16B chunks
#pragma unroll
    for (int i = 0; i < 4; ++i) {
        int c = tid + 256 * i;
        int r = c >> 4, col8 = (c & 15) * 8;
        if (row0 + r < M)
            *(uint4*)(yb + (size_t)(row0 + r) * 128 + col8) = *(const uint4*)&yS[r * 128 + col8];
    }
}

// ---- fused: decode(agg) @ Wg1 -> lrelu -> @ Wg2 + bg2 + x -------------------
// mid stored as single bf16 (LDS 52224 B -> 3 blocks/CU); GEMM2 single-MFMA.
__global__ __launch_bounds__(256) void midout_kernel(
    const ushort* __restrict__ aggb, const float* __restrict__ qv,
    const float* __restrict__ Wf, const float* __restrict__ bfv,
    const ushort* __restrict__ Wg1T, const float* __restrict__ bg1,
    const ushort* __restrict__ Wg2T, const float* __restrict__ bg2,
    const float* __restrict__ x, float* __restrict__ out, int M)
{
    __shared__ ushort Bs[128 * 136];   // 34816 B
    __shared__ ushort Ms[64 * 136];    // 17408 B (52224 total -> 3 blocks/CU)
    const int tid = threadIdx.x;
    const int w = tid >> 6, L = tid & 63, qd = L >> 4, ln = L & 15;
    const int row0 = blockIdx.x * 64;
    const int arow = row0 + w * 16 + ln;

    // A fragments: load agg bf16 row, decode, split in regs
    short8 ah[4], al[4];
    {
        bool ok = arow < M;
        const ushort* base = aggb + (size_t)(ok ? arow : 0) * 128 + qd * 8;
        float q0 = 0.f, q1 = 0.f, q2 = 0.f;
        if (ok) { q0 = qv[arow * 3]; q1 = qv[arow * 3 + 1]; q2 = qv[arow * 3 + 2]; }
        float vb[8];
#pragma unroll
        for (int ks = 0; ks < 4; ++ks) {
            union { uint4 u; ushort s[8]; } a;
            a.u = ok ? *(const uint4*)(base + ks * 32) : make_uint4(0xFF80FF80u, 0xFF80FF80u, 0xFF80FF80u, 0xFF80FF80u);
#pragma unroll
            for (int j = 0; j < 8; ++j) {
                int k = ks * 32 + qd * 8 + j;
                float dec = 0.f;
                if (a.s[j] != 0xFF80u)   // bf16 -inf sentinel = empty segment
                    dec = lrelu(b2f(a.s[j]) + q0 * Wf[k] + q1 * Wf[128 + k] + q2 * Wf[256 + k] + bfv[k]);
                vb[j] = dec;
            }
            split8(vb, ah[ks], al[ks]);
        }
    }

    STAGE_B(Wg1T);
    __syncthreads();
    f32x4 macc[8];
#pragma unroll
    for (int nt = 0; nt < 8; ++nt) macc[nt] = (f32x4){0.f, 0.f, 0.f, 0.f};
    GEMM_CORE_REG(macc, ah, al);
    __syncthreads();   // all waves done reading Bs (Wg1T)

    // mid (bf16) -> Ms; restage Bs = Wg2T
#pragma unroll
    for (int nt = 0; nt < 8; ++nt) {
        int n = nt * 16 + ln;
        float bias = bg1[n];
#pragma unroll
        for (int r = 0; r < 4; ++r)
            Ms[(w * 16 + qd * 4 + r) * 136 + n] = f2b(lrelu(macc[nt][r] + bias));
    }
    STAGE_B(Wg2T);
    __syncthreads();

    // second A fragments from Ms (bf16, single precision path)
    short8 a2[4];
#pragma unroll
    for (int ks = 0; ks < 4; ++ks)
        a2[ks] = *(const short8*)&Ms[(w * 16 + ln) * 136 + ks * 32 + qd * 8];

    f32x4 acc2[8];
#pragma unroll
    for (int nt = 0; nt < 8; ++nt) acc2[nt] = (f32x4){0.f, 0.f, 0.f, 0.f};
#pragma unroll
    for (int ks = 0; ks < 4; ++ks) {
#pragma unroll
        for (int nt = 0; nt < 8; ++nt) {
            short8 bfr = *(const short8*)&Bs[(nt * 16 + ln) * 136 + ks * 32 + qd * 8];
            acc2[nt] = __builtin_amdgcn_mfma_f32_16x16x32_bf16(a2[ks], bfr, acc2[nt], 0, 0, 0);
        }
    }
    __syncthreads();   // done reading Bs (Wg2T) and Ms

    // raw acc -> Bs region (f32 64x132); bg2 + x folded into coalesced copy-out
    float* outS = (float*)Bs;
#pragma unroll
    for (int r = 0; r < 4; ++r) {
        int m = w * 16 + qd * 4 + r;
#pragma unroll
        for (int nt = 0; nt < 8; ++nt)
            outS[m * 132 + nt * 16 + ln] = acc2[nt][r];
    }
    __syncthreads();
#pragma unroll
    for (int i = 0; i < 8; ++i) {
        int c = tid + 256 * i;
        int r = c >> 5, col4 = (c & 31) * 4;
        int gr = row0 + r;
        if (gr < M) {
            float4 o = *(const float4*)&outS[r * 132 + col4];
            float4 bv = *(const float4*)(bg2 + col4);
            float4 xv = *(const float4*)(x + (size_t)gr * 128 + col4);
            o.x += bv.x + xv.x; o.y += bv.y + xv.y;
            o.z += bv.z + xv.z; o.w += bv.w + xv.w;
            *(float4*)(out + (size_t)gr * 128 + col4) = o;
        }
    }
}

// ---- aggregation: agg[i,:] = max over incoming srcs of y'[s,:] (bf16) -------
__global__ __launch_bounds__(256) void agg_kernel(
    const int* __restrict__ offs, const int* __restrict__ srcs,
    const ushort* __restrict__ yb, ushort* __restrict__ aggb, int M)
{
    int wave = threadIdx.x >> 6;
    int lane = threadIdx.x & 63;
    int node = blockIdx.x * 4 + wave;
    if (node >= M) return;
    int o0 = offs[node], o1 = offs[node + 1];
    float a0 = -INFINITY, a1 = -INFINITY;
    const uint* yp = (const uint*)yb;
    int j = o0;
    for (; j + 3 < o1; j += 4) {
        int s0 = srcs[j], s1 = srcs[j + 1], s2 = srcs[j + 2], s3 = srcs[j + 3];
        uint u0 = yp[(size_t)s0 * 64 + lane];
        uint u1 = yp[(size_t)s1 * 64 + lane];
        uint u2 = yp[(size_t)s2 * 64 + lane];
        uint u3 = yp[(size_t)s3 * 64 + lane];
        a0 = fmaxf(a0, fmaxf(fmaxf(__uint_as_float(u0 << 16), __uint_as_float(u1 << 16)),
                             fmaxf(__uint_as_float(u2 << 16), __uint_as_float(u3 << 16))));
        a1 = fmaxf(a1, fmaxf(fmaxf(__uint_as_float(u0 & 0xFFFF0000u), __uint_as_float(u1 & 0xFFFF0000u)),
                             fmaxf(__uint_as_float(u2 & 0xFFFF0000u), __uint_as_float(u3 & 0xFFFF0000u))));
    }
    for (; j < o1; ++j) {
        uint u = yp[(size_t)srcs[j] * 64 + lane];
        a0 = fmaxf(a0, __uint_as_float(u << 16));
        a1 = fmaxf(a1, __uint_as_float(u & 0xFFFF0000u));
    }
    // values are exact bf16 (or -inf) -> repack without rounding
    uint pk = (__float_as_uint(a0) >> 16) | (__float_as_uint(a1) & 0xFFFF0000u);
    ((uint*)aggb)[(size_t)node * 64 + lane] = pk;
}

extern "C" void kernel_launch(void* const* d_in, const int* in_sizes, int n_in,
                              void* d_out, int out_size, void* d_ws, size_t ws_size,
                              hipStream_t stream)
{
    const float* x   = (const float*)d_in[0];
    const float* pos = (const float*)d_in[1];
    const int*   ei  = (const int*)d_in[2];
    const float* Wh1 = (const float*)d_in[3];
    const float* bh1 = (const float*)d_in[4];
    const float* Wh2 = (const float*)d_in[5];
    const float* bh2 = (const float*)d_in[6];
    const float* Wf  = (const float*)d_in[7];
    const float* bf  = (const float*)d_in[8];
    const float* Wg1 = (const float*)d_in[9];
    const float* bg1 = (const float*)d_in[10];
    const float* Wg2 = (const float*)d_in[11];
    const float* bg2 = (const float*)d_in[12];
    float* out = (float*)d_out;

    const int M = in_sizes[0] / 128;   // 50000
    const int E = in_sizes[2] / 2;     // 800000
    const int NBK = (M + 255) >> 8;    // 196 buckets of 256 nodes

    char* ws = (char*)d_ws;
    size_t off = 0;
    auto alloc = [&](size_t bytes) { void* p = ws + off; off += (bytes + 255) & ~255ull; return p; };
    ushort* yb     = (ushort*)alloc((size_t)M * 128 * sizeof(ushort));
    ushort* aggb   = (ushort*)alloc((size_t)M * 128 * sizeof(ushort));
    ushort* WT     = (ushort*)alloc(4 * 16384 * sizeof(ushort));
    float*  q      = (float*)alloc((size_t)M * 3 * sizeof(float));
    int*    offs   = (int*)alloc((size_t)(M + 1) * sizeof(int));
    int*    G      = (int*)alloc((size_t)NBK * 256 * sizeof(int));
    int*    part   = (int*)alloc(256 * sizeof(int));
    int*    bar    = (int*)alloc(256 * sizeof(int));
    uint*   bpairs = (uint*)alloc((size_t)E * sizeof(uint));
    int*    srcs   = (int*)alloc((size_t)E * sizeof(int));

    const int gb = (M + 63) / 64;       // 782

    // zero the grid-barrier state (ws is poisoned before every launch)
    hipMemsetAsync(bar, 0, 256, stream);

    // fused build: wprep + count + scan + partition + bucket CSR (1 kernel)
    build_kernel<<<256, 256, 0, stream>>>(ei, Wh1, Wf, Wg1, Wg2,
                                          WT, G, part, bpairs, offs, srcs,
                                          bar, E, M, NBK);

    // fused pipeline
    hy_kernel<<<gb, 256, 0, stream>>>(x, WT, bh1, Wh2, bh2,
                                      WT + 16384, Wf, pos, q, yb, M);
    agg_kernel<<<(M + 3) / 4, 256, 0, stream>>>(offs, srcs, yb, aggb, M);
    midout_kernel<<<gb, 256, 0, stream>>>(aggb, q, Wf, bf,
                                          WT + 2 * 16384, bg1,
                                          WT + 3 * 16384, bg2, x, out, M);
}

// Round 9
// 218.390 us; speedup vs baseline: 1.3864x; 1.3864x over previous
//
#include <hip/hip_runtime.h>
#include <cfloat>
#include <cmath>

#define NEG_SLOPE 0.01f

typedef __attribute__((ext_vector_type(8))) short short8;
typedef __attribute__((ext_vector_type(4))) float f32x4;

__device__ __forceinline__ float lrelu(float v) { return v >= 0.0f ? v : NEG_SLOPE * v; }

// f32 -> bf16 round-to-nearest-even (monotone; identity on exact bf16 values)
__device__ __forceinline__ ushort f2b(float f) {
    unsigned u = __float_as_uint(f);
    u += 0x7fffu + ((u >> 16) & 1u);
    return (ushort)(u >> 16);
}
__device__ __forceinline__ float b2f(ushort s) { return __uint_as_float(((unsigned)s) << 16); }

// split 8 consecutive f32 into hi/lo bf16 fragments (register-resident)
__device__ __forceinline__ void split8(const float* v, short8& hi, short8& lo) {
#pragma unroll
    for (int j = 0; j < 8; ++j) {
        ushort h = f2b(v[j]);
        hi[j] = (short)h;
        lo[j] = (short)f2b(v[j] - b2f(h));
    }
}

// ============ build step 1: per-block bucket histogram + weight prep =========
// grid MUST be exactly 256 blocks x 256 threads.
// Buckets of 256 nodes by dst>>8; NBK = ceil(M/256) <= 256.
// G[bucket*256 + block] = per-block bucket counts.
// Weight prep (independent work): WT[mat][n*128+k], mat 0=Wh1, 1=Wf[3:], 2=Wg1, 3=Wg2.
__global__ __launch_bounds__(256) void count_wprep_kernel(
    const int* __restrict__ ei,
    const float* __restrict__ Wh1, const float* __restrict__ Wf,
    const float* __restrict__ Wg1, const float* __restrict__ Wg2,
    ushort* __restrict__ WT, int* __restrict__ G, int E, int NBK)
{
    __shared__ int cnt[256];
    const int t = threadIdx.x;
    const int b = blockIdx.x;

    // weight prep: exactly 4*16384 = 65536 entries over 256x256 threads
    {
        int tt = b * 256 + t;
        int mat = tt >> 14;
        int idx = tt & 16383;
        int n = idx >> 7, k = idx & 127;
        float v;
        if (mat == 0)      v = Wh1[k * 128 + n];
        else if (mat == 1) v = Wf[(k + 3) * 128 + n];
        else if (mat == 2) v = Wg1[k * 128 + n];
        else               v = Wg2[k * 128 + n];
        WT[(tt - idx) + n * 128 + k] = f2b(v);
    }

    cnt[t] = 0;
    __syncthreads();
    for (int e = b * 256 + t; e < E; e += 65536)
        atomicAdd(&cnt[ei[E + e] >> 8], 1);
    __syncthreads();
    if (t < NBK) G[t * 256 + b] = cnt[t];
}

// ---- build step 2: per-chunk sums of G (NG = NBK*256 entries) ----
__global__ __launch_bounds__(256) void scanA_kernel(
    const int* __restrict__ G, int* __restrict__ partial)
{
    __shared__ int s[256];
    int i = blockIdx.x * 256 + threadIdx.x;
    s[threadIdx.x] = G[i];
    __syncthreads();
    for (int d = 128; d > 0; d >>= 1) {
        if (threadIdx.x < d) s[threadIdx.x] += s[threadIdx.x + d];
        __syncthreads();
    }
    if (threadIdx.x == 0) partial[blockIdx.x] = s[0];
}

// ---- build step 3: every block recomputes the partial scan, applies locally --
__global__ __launch_bounds__(256) void scanBC_kernel(
    int* __restrict__ G, const int* __restrict__ partial, int NB)
{
    __shared__ int s[256];
    __shared__ int base;
    const int t = threadIdx.x;
    int v = (t < NB) ? partial[t] : 0;
    s[t] = v;
    __syncthreads();
    for (int d = 1; d < 256; d <<= 1) {
        int a = (t >= d) ? s[t - d] : 0;
        __syncthreads();
        s[t] += a;
        __syncthreads();
    }
    if (t == blockIdx.x) base = s[t] - v;   // exclusive sum of chunks before this one
    __syncthreads();

    int i = blockIdx.x * 256 + t;
    int g = G[i];
    s[t] = g;
    __syncthreads();
    for (int d = 1; d < 256; d <<= 1) {
        int a = (t >= d) ? s[t - d] : 0;
        __syncthreads();
        s[t] += a;
        __syncthreads();
    }
    G[i] = base + s[t] - g;                  // exclusive global base
}

// ---- build step 4: partition edges into bucket regions ----
// bpairs[p] = src | (dst_local<<24). grid MUST be 256 blocks.
__global__ __launch_bounds__(256) void partition_kernel(
    const int* __restrict__ ei, const int* __restrict__ G,
    uint* __restrict__ bpairs, int E, int NBK)
{
    __shared__ int cur[256];
    const int tid = threadIdx.x;
    if (tid < NBK) cur[tid] = G[tid * 256 + blockIdx.x];
    __syncthreads();
    for (int e = blockIdx.x * 256 + tid; e < E; e += 65536) {
        int src = ei[e];
        int dst = ei[E + e];
        int p = atomicAdd(&cur[dst >> 8], 1);
        bpairs[p] = (uint)src | ((uint)(dst & 255) << 24);
    }
}

// ---- build step 5: per-bucket local CSR (deg -> scan -> scatter) ----
__global__ __launch_bounds__(256) void bucket_csr_kernel(
    const uint* __restrict__ bpairs, const int* __restrict__ G,
    int* __restrict__ offs, int* __restrict__ srcs, int E, int M, int NBK)
{
    __shared__ int deg[256], scn[256], cur[256];
    const int b = blockIdx.x;
    const int t = threadIdx.x;
    const int base = G[b * 256];
    const int end  = (b + 1 < NBK) ? G[(b + 1) * 256] : E;
    deg[t] = 0;
    __syncthreads();
    for (int p = base + t; p < end; p += 256)
        atomicAdd(&deg[bpairs[p] >> 24], 1);
    __syncthreads();
    scn[t] = deg[t];
    __syncthreads();
    for (int d = 1; d < 256; d <<= 1) {
        int a = (t >= d) ? scn[t - d] : 0;
        __syncthreads();
        scn[t] += a;
        __syncthreads();
    }
    int excl = scn[t] - deg[t];
    cur[t] = excl;
    int node = b * 256 + t;
    if (node < M) offs[node] = base + excl;
    if (node == M - 1 || (b == NBK - 1 && t == 255)) offs[M] = E;
    __syncthreads();
    for (int p = base + t; p < end; p += 256) {
        uint pk = bpairs[p];
        int qpos = atomicAdd(&cur[pk >> 24], 1);
        srcs[base + qpos] = (int)(pk & 0xFFFFFFu);
    }
}

// ---------------- MFMA GEMM skeleton ----------------
// block = 256 thr = 4 waves; tile 64 rows x 128 cols; K = 128 (4 steps of 32).
// wave w covers rows [w*16, w*16+16); lane: qd = L>>4, ln = L&15.
// A-operand in registers (hi/lo split, 2 MFMAs per fragment).
// b_frag: WT[n = nt*16+ln][k = ks*32+qd*8+j]  (LDS Bs, stride 136 bf16)
// D:      C[m = w*16+qd*4+r][n = nt*16+ln] = acc[nt][r]

#define GEMM_CORE_REG(ACC, AH, AL)                                              \
    {                                                                           \
        _Pragma("unroll")                                                       \
        for (int ks = 0; ks < 4; ++ks) {                                        \
            _Pragma("unroll")                                                   \
            for (int nt = 0; nt < 8; ++nt) {                                    \
                short8 bfr = *(const short8*)&Bs[(nt * 16 + ln) * 136 + ks * 32 + qd * 8]; \
                ACC[nt] = __builtin_amdgcn_mfma_f32_16x16x32_bf16(AL[ks], bfr, ACC[nt], 0, 0, 0); \
                ACC[nt] = __builtin_amdgcn_mfma_f32_16x16x32_bf16(AH[ks], bfr, ACC[nt], 0, 0, 0); \
            }                                                                   \
        }                                                                       \
    }

#define STAGE_B(WTP)                                                            \
    {                                                                           \
        _Pragma("unroll")                                                       \
        for (int i = 0; i < 8; ++i) {                                           \
            int c = tid + 256 * i;                                              \
            int r = c >> 4, col8 = (c & 15) * 8;                                \
            *(uint4*)&Bs[r * 136 + col8] = *(const uint4*)((WTP) + r * 128 + col8); \
        }                                                                       \
    }

// ---- fused: h1=lrelu(x@Wh1+bh1); q=tanh(h1@Wh2+bh2)-pos; y'=x@Wfx+pos.Wrel --
__global__ __launch_bounds__(256) void hy_kernel(
    const float* __restrict__ x, const ushort* __restrict__ Wh1T,
    const float* __restrict__ bh1, const float* __restrict__ Wh2,
    const float* __restrict__ bh2, const ushort* __restrict__ WfxT,
    const float* __restrict__ Wf, const float* __restrict__ pos,
    float* __restrict__ q, ushort* __restrict__ yb, int M)
{
    __shared__ ushort Bs[128 * 136];   // 34816 B
    __shared__ ushort yS[64 * 128];    // 16384 B  (51200 total -> 3 blocks/CU)
    const int tid = threadIdx.x;
    const int w = tid >> 6, L = tid & 63, qd = L >> 4, ln = L & 15;
    const int row0 = blockIdx.x * 64;
    const int arow = row0 + w * 16 + ln;

    // A fragments straight from global x, hi/lo split in regs
    short8 ah[4], al[4];
    {
        const float* base = x + (size_t)((arow < M) ? arow : 0) * 128 + qd * 8;
        float vb[8];
#pragma unroll
        for (int ks = 0; ks < 4; ++ks) {
            float4 v0 = make_float4(0.f, 0.f, 0.f, 0.f), v1 = v0;
            if (arow < M) {
                v0 = *(const float4*)(base + ks * 32);
                v1 = *(const float4*)(base + ks * 32 + 4);
            }
            vb[0] = v0.x; vb[1] = v0.y; vb[2] = v0.z; vb[3] = v0.w;
            vb[4] = v1.x; vb[5] = v1.y; vb[6] = v1.z; vb[7] = v1.w;
            split8(vb, ah[ks], al[ks]);
        }
    }

    STAGE_B(Wh1T);
    __syncthreads();
    f32x4 acc1[8];
#pragma unroll
    for (int nt = 0; nt < 8; ++nt) acc1[nt] = (f32x4){0.f, 0.f, 0.f, 0.f};
    GEMM_CORE_REG(acc1, ah, al);
    __syncthreads();

    STAGE_B(WfxT);
    __syncthreads();
    f32x4 acc2[8];
#pragma unroll
    for (int nt = 0; nt < 8; ++nt) acc2[nt] = (f32x4){0.f, 0.f, 0.f, 0.f};
    GEMM_CORE_REG(acc2, ah, al);
    __syncthreads();

    // h1 (f32) into Bs region; y' (bf16) into yS
    float* h1s = (float*)Bs;   // 64 x 132 f32 = 33792 B
#pragma unroll
    for (int nt = 0; nt < 8; ++nt) {
        int n = nt * 16 + ln;
        float bias = bh1[n];
#pragma unroll
        for (int r = 0; r < 4; ++r)
            h1s[(w * 16 + qd * 4 + r) * 132 + n] = lrelu(acc1[nt][r] + bias);
    }
#pragma unroll
    for (int r = 0; r < 4; ++r) {
        int m = w * 16 + qd * 4 + r;
        int gm = row0 + m;
        float p0 = 0.f, p1 = 0.f, p2 = 0.f;
        if (gm < M) { p0 = pos[gm * 3]; p1 = pos[gm * 3 + 1]; p2 = pos[gm * 3 + 2]; }
#pragma unroll
        for (int nt = 0; nt < 8; ++nt) {
            int n = nt * 16 + ln;
            yS[m * 128 + n] = f2b(acc2[nt][r] + p0 * Wf[n] + p1 * Wf[128 + n] + p2 * Wf[256 + n]);
        }
    }
    __syncthreads();

    // q reduction (threads 0..191)
    int row = tid & 63, cc = tid >> 6;
    if (cc < 3 && row0 + row < M) {
        float s = 0.f;
#pragma unroll
        for (int k4 = 0; k4 < 32; ++k4) {
            float4 h = *(const float4*)&h1s[row * 132 + k4 * 4];
            s += h.x * Wh2[(k4 * 4 + 0) * 3 + cc] + h.y * Wh2[(k4 * 4 + 1) * 3 + cc]
               + h.z * Wh2[(k4 * 4 + 2) * 3 + cc] + h.w * Wh2[(k4 * 4 + 3) * 3 + cc];
        }
        q[(row0 + row) * 3 + cc] = tanhf(s + bh2[cc]) - pos[(row0 + row) * 3 + cc];
    }
    // y' copy-out: 1024 x 16B chunks
#pragma unroll
    for (int i = 0; i < 4; ++i) {
        int c = tid + 256 * i;
        int r = c >> 4, col8 = (c & 15) * 8;
        if (row0 + r < M)
            *(uint4*)(yb + (size_t)(row0 + r) * 128 + col8) = *(const uint4*)&yS[r * 128 + col8];
    }
}

// ---- fused: decode(agg) @ Wg1 -> lrelu -> @ Wg2 + bg2 + x -------------------
// mid stored as single bf16 (LDS 52224 B -> 3 blocks/CU); GEMM2 single-MFMA.
__global__ __launch_bounds__(256) void midout_kernel(
    const ushort* __restrict__ aggb, const float* __restrict__ qv,
    const float* __restrict__ Wf, const float* __restrict__ bfv,
    const ushort* __restrict__ Wg1T, const float* __restrict__ bg1,
    const ushort* __restrict__ Wg2T, const float* __restrict__ bg2,
    const float* __restrict__ x, float* __restrict__ out, int M)
{
    __shared__ ushort Bs[128 * 136];   // 34816 B
    __shared__ ushort Ms[64 * 136];    // 17408 B (52224 total -> 3 blocks/CU)
    const int tid = threadIdx.x;
    const int w = tid >> 6, L = tid & 63, qd = L >> 4, ln = L & 15;
    const int row0 = blockIdx.x * 64;
    const int arow = row0 + w * 16 + ln;

    // A fragments: load agg bf16 row, decode, split in regs
    short8 ah[4], al[4];
    {
        bool ok = arow < M;
        const ushort* base = aggb + (size_t)(ok ? arow : 0) * 128 + qd * 8;
        float q0 = 0.f, q1 = 0.f, q2 = 0.f;
        if (ok) { q0 = qv[arow * 3]; q1 = qv[arow * 3 + 1]; q2 = qv[arow * 3 + 2]; }
        float vb[8];
#pragma unroll
        for (int ks = 0; ks < 4; ++ks) {
            union { uint4 u; ushort s[8]; } a;
            a.u = ok ? *(const uint4*)(base + ks * 32) : make_uint4(0xFF80FF80u, 0xFF80FF80u, 0xFF80FF80u, 0xFF80FF80u);
#pragma unroll
            for (int j = 0; j < 8; ++j) {
                int k = ks * 32 + qd * 8 + j;
                float dec = 0.f;
                if (a.s[j] != 0xFF80u)   // bf16 -inf sentinel = empty segment
                    dec = lrelu(b2f(a.s[j]) + q0 * Wf[k] + q1 * Wf[128 + k] + q2 * Wf[256 + k] + bfv[k]);
                vb[j] = dec;
            }
            split8(vb, ah[ks], al[ks]);
        }
    }

    STAGE_B(Wg1T);
    __syncthreads();
    f32x4 macc[8];
#pragma unroll
    for (int nt = 0; nt < 8; ++nt) macc[nt] = (f32x4){0.f, 0.f, 0.f, 0.f};
    GEMM_CORE_REG(macc, ah, al);
    __syncthreads();   // all waves done reading Bs (Wg1T)

    // mid (bf16) -> Ms; restage Bs = Wg2T
#pragma unroll
    for (int nt = 0; nt < 8; ++nt) {
        int n = nt * 16 + ln;
        float bias = bg1[n];
#pragma unroll
        for (int r = 0; r < 4; ++r)
            Ms[(w * 16 + qd * 4 + r) * 136 + n] = f2b(lrelu(macc[nt][r] + bias));
    }
    STAGE_B(Wg2T);
    __syncthreads();

    // second A fragments from Ms (bf16, single precision path)
    short8 a2[4];
#pragma unroll
    for (int ks = 0; ks < 4; ++ks)
        a2[ks] = *(const short8*)&Ms[(w * 16 + ln) * 136 + ks * 32 + qd * 8];

    f32x4 acc2[8];
#pragma unroll
    for (int nt = 0; nt < 8; ++nt) acc2[nt] = (f32x4){0.f, 0.f, 0.f, 0.f};
#pragma unroll
    for (int ks = 0; ks < 4; ++ks) {
#pragma unroll
        for (int nt = 0; nt < 8; ++nt) {
            short8 bfr = *(const short8*)&Bs[(nt * 16 + ln) * 136 + ks * 32 + qd * 8];
            acc2[nt] = __builtin_amdgcn_mfma_f32_16x16x32_bf16(a2[ks], bfr, acc2[nt], 0, 0, 0);
        }
    }
    __syncthreads();   // done reading Bs (Wg2T) and Ms

    // raw acc -> Bs region (f32 64x132); bg2 + x folded into coalesced copy-out
    float* outS = (float*)Bs;
#pragma unroll
    for (int r = 0; r < 4; ++r) {
        int m = w * 16 + qd * 4 + r;
#pragma unroll
        for (int nt = 0; nt < 8; ++nt)
            outS[m * 132 + nt * 16 + ln] = acc2[nt][r];
    }
    __syncthreads();
#pragma unroll
    for (int i = 0; i < 8; ++i) {
        int c = tid + 256 * i;
        int r = c >> 5, col4 = (c & 31) * 4;
        int gr = row0 + r;
        if (gr < M) {
            float4 o = *(const float4*)&outS[r * 132 + col4];
            float4 bv = *(const float4*)(bg2 + col4);
            float4 xv = *(const float4*)(x + (size_t)gr * 128 + col4);
            o.x += bv.x + xv.x; o.y += bv.y + xv.y;
            o.z += bv.z + xv.z; o.w += bv.w + xv.w;
            *(float4*)(out + (size_t)gr * 128 + col4) = o;
        }
    }
}

// ---- aggregation: agg[i,:] = max over incoming srcs of y'[s,:] (bf16) -------
__global__ __launch_bounds__(256) void agg_kernel(
    const int* __restrict__ offs, const int* __restrict__ srcs,
    const ushort* __restrict__ yb, ushort* __restrict__ aggb, int M)
{
    int wave = threadIdx.x >> 6;
    int lane = threadIdx.x & 63;
    int node = blockIdx.x * 4 + wave;
    if (node >= M) return;
    int o0 = offs[node], o1 = offs[node + 1];
    float a0 = -INFINITY, a1 = -INFINITY;
    const uint* yp = (const uint*)yb;
    int j = o0;
    for (; j + 3 < o1; j += 4) {
        int s0 = srcs[j], s1 = srcs[j + 1], s2 = srcs[j + 2], s3 = srcs[j + 3];
        uint u0 = yp[(size_t)s0 * 64 + lane];
        uint u1 = yp[(size_t)s1 * 64 + lane];
        uint u2 = yp[(size_t)s2 * 64 + lane];
        uint u3 = yp[(size_t)s3 * 64 + lane];
        a0 = fmaxf(a0, fmaxf(fmaxf(__uint_as_float(u0 << 16), __uint_as_float(u1 << 16)),
                             fmaxf(__uint_as_float(u2 << 16), __uint_as_float(u3 << 16))));
        a1 = fmaxf(a1, fmaxf(fmaxf(__uint_as_float(u0 & 0xFFFF0000u), __uint_as_float(u1 & 0xFFFF0000u)),
                             fmaxf(__uint_as_float(u2 & 0xFFFF0000u), __uint_as_float(u3 & 0xFFFF0000u))));
    }
    for (; j < o1; ++j) {
        uint u = yp[(size_t)srcs[j] * 64 + lane];
        a0 = fmaxf(a0, __uint_as_float(u << 16));
        a1 = fmaxf(a1, __uint_as_float(u & 0xFFFF0000u));
    }
    // values are exact bf16 (or -inf) -> repack without rounding
    uint pk = (__float_as_uint(a0) >> 16) | (__float_as_uint(a1) & 0xFFFF0000u);
    ((uint*)aggb)[(size_t)node * 64 + lane] = pk;
}

extern "C" void kernel_launch(void* const* d_in, const int* in_sizes, int n_in,
                              void* d_out, int out_size, void* d_ws, size_t ws_size,
                              hipStream_t stream)
{
    const float* x   = (const float*)d_in[0];
    const float* pos = (const float*)d_in[1];
    const int*   ei  = (const int*)d_in[2];
    const float* Wh1 = (const float*)d_in[3];
    const float* bh1 = (const float*)d_in[4];
    const float* Wh2 = (const float*)d_in[5];
    const float* bh2 = (const float*)d_in[6];
    const float* Wf  = (const float*)d_in[7];
    const float* bf  = (const float*)d_in[8];
    const float* Wg1 = (const float*)d_in[9];
    const float* bg1 = (const float*)d_in[10];
    const float* Wg2 = (const float*)d_in[11];
    const float* bg2 = (const float*)d_in[12];
    float* out = (float*)d_out;

    const int M = in_sizes[0] / 128;   // 50000
    const int E = in_sizes[2] / 2;     // 800000
    const int NBK = (M + 255) >> 8;    // 196 buckets of 256 nodes

    char* ws = (char*)d_ws;
    size_t off = 0;
    auto alloc = [&](size_t bytes) { void* p = ws + off; off += (bytes + 255) & ~255ull; return p; };
    ushort* yb     = (ushort*)alloc((size_t)M * 128 * sizeof(ushort));
    ushort* aggb   = (ushort*)alloc((size_t)M * 128 * sizeof(ushort));
    ushort* WT     = (ushort*)alloc(4 * 16384 * sizeof(ushort));
    float*  q      = (float*)alloc((size_t)M * 3 * sizeof(float));
    int*    offs   = (int*)alloc((size_t)(M + 1) * sizeof(int));
    int*    G      = (int*)alloc((size_t)NBK * 256 * sizeof(int));
    int*    part   = (int*)alloc(256 * sizeof(int));
    uint*   bpairs = (uint*)alloc((size_t)E * sizeof(uint));
    int*    srcs   = (int*)alloc((size_t)E * sizeof(int));

    const int gb = (M + 63) / 64;       // 782

    // bucketed CSR build (no global atomics, no grid barriers)
    count_wprep_kernel<<<256, 256, 0, stream>>>(ei, Wh1, Wf, Wg1, Wg2, WT, G, E, NBK);
    scanA_kernel<<<NBK, 256, 0, stream>>>(G, part);
    scanBC_kernel<<<NBK, 256, 0, stream>>>(G, part, NBK);
    partition_kernel<<<256, 256, 0, stream>>>(ei, G, bpairs, E, NBK);
    bucket_csr_kernel<<<NBK, 256, 0, stream>>>(bpairs, G, offs, srcs, E, M, NBK);

    // fused pipeline
    hy_kernel<<<gb, 256, 0, stream>>>(x, WT, bh1, Wh2, bh2,
                                      WT + 16384, Wf, pos, q, yb, M);
    agg_kernel<<<(M + 3) / 4, 256, 0, stream>>>(offs, srcs, yb, aggb, M);
    midout_kernel<<<gb, 256, 0, stream>>>(aggb, q, Wf, bf,
                                          WT + 2 * 16384, bg1,
                                          WT + 3 * 16384, bg2, x, out, M);
}